// Round 5
// baseline (283.706 us; speedup 1.0000x reference)
//
#include <hip/hip_runtime.h>

#define BT   8192
#define MS   8      // samples per fused block
#define XBUF (MS * 656)   // halves per Xs buffer

typedef _Float16 half8  __attribute__((ext_vector_type(8)));
typedef _Float16 half4v __attribute__((ext_vector_type(4)));
typedef float    floatx4  __attribute__((ext_vector_type(4)));
typedef float    floatx16 __attribute__((ext_vector_type(16)));

// ---------------- K0a: conv weight pre-transform -> W3[step][256n][32c] ----
__global__ __launch_bounds__(256) void w3_transform(
    const float* __restrict__ weight, _Float16* __restrict__ W3)
{
    const int n = blockIdx.x;      // 0..255  (= kbank*64 + o)
    const int c = threadIdx.x;     // 0..255
    const float* src = weight + ((size_t)n * 256 + c) * 9;
    const int cc = c >> 5, ci = c & 31;
    #pragma unroll
    for (int ij = 0; ij < 9; ++ij) {
        W3[((size_t)(cc * 9 + ij) * 256 + n) * 32 + ci] = (_Float16)src[ij];
    }
}

// ---------------- K0b: KAN + fc1 weight pre-transform ---------------------
__global__ __launch_bounds__(256) void wk3_transform(
    const float* __restrict__ base_w, const float* __restrict__ spline_w,
    const float* __restrict__ scaler, const float* __restrict__ fc1_w,
    _Float16* __restrict__ Wk3, _Float16* __restrict__ Wf3)
{
    const int st = blockIdx.x;
    const int tid = threadIdx.x;
    if (st < 72) {
        #pragma unroll
        for (int u = 0; u < 8; ++u) {
            const int idx = u * 256 + tid;       // n*32 + kk
            const int n = idx >> 5, kk = idx & 31;
            const int k = st * 32 + kk;
            float v;
            if (k < 256) {
                v = base_w[n * 256 + k];
            } else {
                const int r = k - 256;
                const int i = r >> 3, g = r & 7;
                v = spline_w[((size_t)n * 256 + i) * 8 + g] * scaler[n * 256 + i];
            }
            Wk3[(size_t)st * 2048 + idx] = (_Float16)v;
        }
    } else {
        const int st2 = st - 72;                 // 0..7
        #pragma unroll
        for (int u = 0; u < 8; ++u) {
            const int idx = u * 256 + tid;
            const int n = idx >> 5, kk = idx & 31;
            Wf3[(size_t)st2 * 2048 + idx] = (_Float16)fc1_w[n * 256 + st2 * 32 + kk];
        }
    }
}

// B-spline bases: divisions folded to compile-time reciprocals
__device__ __forceinline__ void bases8(float xv, _Float16* dst) {
    float g[12];
    #pragma unroll
    for (int u = 0; u < 12; ++u) g[u] = (float)(u - 3) * 0.4f - 1.0f;
    float dt[12];
    #pragma unroll
    for (int u = 0; u < 12; ++u) dt[u] = xv - g[u];
    float t0[11];
    #pragma unroll
    for (int t = 0; t < 11; ++t)
        t0[t] = (xv >= g[t] && xv < g[t + 1]) ? 1.f : 0.f;
    float t1[10];
    #pragma unroll
    for (int t = 0; t < 10; ++t)
        t1[t] = dt[t] * (1.0f / (g[t + 1] - g[t])) * t0[t]
              - dt[t + 2] * (1.0f / (g[t + 2] - g[t + 1])) * t0[t + 1];
    float t2[9];
    #pragma unroll
    for (int t = 0; t < 9; ++t)
        t2[t] = dt[t] * (1.0f / (g[t + 2] - g[t])) * t1[t]
              - dt[t + 3] * (1.0f / (g[t + 3] - g[t + 1])) * t1[t + 1];
    half8 hb;
    #pragma unroll
    for (int t = 0; t < 8; ++t) {
        float b = dt[t] * (1.0f / (g[t + 3] - g[t])) * t2[t]
                - dt[t + 4] * (1.0f / (g[t + 4] - g[t + 1])) * t2[t + 1];
        hb[t] = (_Float16)b;
    }
    *(half8*)dst = hb;
}

// ---------------- Fused: attn + dyn-conv (MFMA) + KAN (MFMA) -> out -------
// 256 threads = 4 waves; wave cg owns o-tile cg (all 4 kbanks, both row-tiles)
__global__ __launch_bounds__(256, 4) void fused_kernel(
    const float* __restrict__ x, const _Float16* __restrict__ W3,
    const _Float16* __restrict__ Wk3, const _Float16* __restrict__ Wf3,
    const float* __restrict__ bias, const float* __restrict__ fc1_b,
    const float* __restrict__ fc2_w, const float* __restrict__ fc2_b,
    float* __restrict__ out)
{
    // Overlay: phase A = Xs dbuf (2*10496 B) + Pl (4224 B) = 25216 B
    //          phase B = Act (8*2312 fp16 = 36992 B)
    __shared__ __align__(16) char smem[MS * 2312 * 2];
    __shared__ float hid_lds[MS * 68];
    __shared__ float attn_s[MS][4];

    _Float16* Xs  = (_Float16*)smem;                  // two buffers of XBUF
    _Float16* Pl  = (_Float16*)(smem + 2 * XBUF * 2); // pooled, fp16 A-layout
    _Float16* Act = (_Float16*)smem;

    const int tid = threadIdx.x;
    const int wv = tid >> 6, lane = tid & 63;
    const int nl = lane & 15, q = lane >> 4;
    const int cg = wv;                 // o-tile
    const int b0 = blockIdx.x * MS;

    // conv A-fragment base (halves): sample + pixel + k
    const int posr = nl & 3;
    const int aLane = (nl >> 2) * 656 + ((posr >> 1) * 4 + (posr & 1)) * 40 + q * 8;
    int lbW[4];
    #pragma unroll
    for (int kb = 0; kb < 4; ++kb) lbW[kb] = ((cg + 4 * kb) * 16 + nl) * 32 + q * 8;

    // x staging: thread -> (sample s_, channel cch)
    const int s_ = tid >> 5, cch = tid & 31;
    const float* xg = x + ((size_t)(b0 + s_) * 256 + cch) * 16;

    floatx4 acc[2][4];
    #pragma unroll
    for (int rt = 0; rt < 2; ++rt)
        #pragma unroll
        for (int kb = 0; kb < 4; ++kb) acc[rt][kb] = floatx4{0.f, 0.f, 0.f, 0.f};

    // prologue: stage chunk 0, prefetch chunk 1
    floatx16 r = *(const floatx16*)xg;
    {
        _Float16* xd = &Xs[s_ * 656 + cch];
        #pragma unroll
        for (int p = 0; p < 16; ++p) xd[p * 40] = (_Float16)r[p];
        float sm = 0.f;
        #pragma unroll
        for (int p = 0; p < 16; ++p) sm += r[p];
        Pl[s_ * 264 + cch] = (_Float16)(sm * (1.0f / 16.0f));
    }
    r = *(const floatx16*)(xg + 512);
    __syncthreads();

    for (int cc = 0; cc < 8; ++cc) {
        const int cur = cc & 1;
        if (cc < 7) {       // stage chunk cc+1 into other buffer (no hazard: barrier cc-1)
            _Float16* xd = &Xs[(cur ^ 1) * XBUF + s_ * 656 + cch];
            #pragma unroll
            for (int p = 0; p < 16; ++p) xd[p * 40] = (_Float16)r[p];
            float sm = 0.f;
            #pragma unroll
            for (int p = 0; p < 16; ++p) sm += r[p];
            Pl[s_ * 264 + (cc + 1) * 32 + cch] = (_Float16)(sm * (1.0f / 16.0f));
        }
        if (cc < 6) r = *(const floatx16*)(xg + (cc + 2) * 512);

        const _Float16* wst = W3 + (size_t)cc * 9 * 8192;
        const _Float16* xb = &Xs[cur * XBUF + aLane];
        half8 bFc[4];
        #pragma unroll
        for (int kb = 0; kb < 4; ++kb) bFc[kb] = *(const half8*)(wst + lbW[kb]);
        #pragma unroll
        for (int ij = 0; ij < 9; ++ij) {
            half8 bFn[4];
            if (ij < 8) {
                #pragma unroll
                for (int kb = 0; kb < 4; ++kb)
                    bFn[kb] = *(const half8*)(wst + (ij + 1) * 8192 + lbW[kb]);
            }
            const int p0 = (ij / 3) * 4 + (ij % 3);
            half8 aF[2];
            #pragma unroll
            for (int rt = 0; rt < 2; ++rt)
                aF[rt] = *(const half8*)&xb[rt * 2624 + p0 * 40];
            #pragma unroll
            for (int rt = 0; rt < 2; ++rt)
                #pragma unroll
                for (int kb = 0; kb < 4; ++kb)
                    acc[rt][kb] = __builtin_amdgcn_mfma_f32_16x16x32_f16(aF[rt], bFc[kb], acc[rt][kb], 0, 0, 0);
            #pragma unroll
            for (int kb = 0; kb < 4; ++kb) bFc[kb] = bFn[kb];
        }
        __syncthreads();
    }

    // ---- fc1 via MFMA: all 4 waves, wave cg -> h-tile cg; rows 0..7 valid ----
    {
        floatx4 a1 = floatx4{0.f, 0.f, 0.f, 0.f};
        const _Float16* wfb = Wf3 + ((cg * 16 + nl) * 32 + q * 8);
        const _Float16* pb = &Pl[(nl & 7) * 264 + q * 8];
        #pragma unroll
        for (int st = 0; st < 8; ++st) {
            const half8 aF = *(const half8*)(pb + st * 32);
            const half8 bF = *(const half8*)(wfb + st * 2048);
            a1 = __builtin_amdgcn_mfma_f32_16x16x32_f16(aF, bF, a1, 0, 0, 0);
        }
        if (q < 2) {
            const int h = cg * 16 + nl;
            const float fb = fc1_b[h];
            #pragma unroll
            for (int reg = 0; reg < 4; ++reg)
                hid_lds[(q * 4 + reg) * 68 + h] = fmaxf(a1[reg] + fb, 0.f);
        }
    }
    __syncthreads();

    // ---- fc2 + softmax (wave 0, lanes 0..31) ----
    if (wv == 0) {
        const int s = lane >> 2, kb = lane & 3;
        if (s < 8) {
            float l = fc2_b[kb];
            #pragma unroll 8
            for (int h = 0; h < 64; ++h) l += hid_lds[s * 68 + h] * fc2_w[kb * 64 + h];
            float m = fmaxf(l, __shfl_xor(l, 1));
            m = fmaxf(m, __shfl_xor(m, 2));
            const float e = __expf((l - m) * (1.0f / 34.0f));
            float sm = e + __shfl_xor(e, 1);
            sm += __shfl_xor(sm, 2);
            attn_s[s][kb] = e / sm;
        }
    }
    __syncthreads();   // attn ready; Xs/Pl dead -> Act region free

    // ---- epilogue: attn-combine in registers -> silu + bases -> Act ----
    {
        const int o = cg * 16 + nl;
        const float bb0 = bias[o], bb1 = bias[64 + o], bb2 = bias[128 + o], bb3 = bias[192 + o];
        #pragma unroll
        for (int rt = 0; rt < 2; ++rt) {
            const int s = rt * 4 + q;
            const float a0 = attn_s[s][0], a1 = attn_s[s][1], a2 = attn_s[s][2], a3 = attn_s[s][3];
            const float badd = a0 * bb0 + a1 * bb1 + a2 * bb2 + a3 * bb3;
            float f[4];
            #pragma unroll
            for (int e = 0; e < 4; ++e)
                f[e] = a0 * acc[rt][0][e] + a1 * acc[rt][1][e]
                     + a2 * acc[rt][2][e] + a3 * acc[rt][3][e] + badd;
            half4v sv;
            #pragma unroll
            for (int e = 0; e < 4; ++e) {
                const float ex = __expf(-f[e]);
                sv[e] = (_Float16)(f[e] * __builtin_amdgcn_rcpf(1.f + ex));
            }
            *(half4v*)&Act[s * 2312 + o * 4] = sv;
            #pragma unroll
            for (int e = 0; e < 4; ++e)
                bases8(f[e], &Act[s * 2312 + 256 + (o * 4 + e) * 8]);
        }
    }
    __syncthreads();

    // ---- KAN GEMM: wave cg -> o-tile cg, all 72 K-steps, rows 0..7 valid ----
    {
        floatx4 a2 = floatx4{0.f, 0.f, 0.f, 0.f};
        const _Float16* wkb = Wk3 + ((size_t)(cg * 16 + nl) * 32 + q * 8);
        const _Float16* ab = &Act[(nl & 7) * 2312 + q * 8];
        half8 bFc = *(const half8*)(wkb);
        #pragma unroll 8
        for (int st = 0; st < 72; ++st) {
            half8 bFn;
            if (st < 71) bFn = *(const half8*)(wkb + (size_t)(st + 1) * 2048);
            const half8 aF = *(const half8*)(ab + st * 32);
            a2 = __builtin_amdgcn_mfma_f32_16x16x32_f16(aF, bFc, a2, 0, 0, 0);
            bFc = bFn;
        }
        if (q < 2) {
            #pragma unroll
            for (int reg = 0; reg < 4; ++reg)
                out[(size_t)(b0 + q * 4 + reg) * 64 + cg * 16 + nl] = a2[reg];
        }
    }
}

extern "C" void kernel_launch(void* const* d_in, const int* in_sizes, int n_in,
                              void* d_out, int out_size, void* d_ws, size_t ws_size,
                              hipStream_t stream) {
    const float* x          = (const float*)d_in[0];
    const float* weight     = (const float*)d_in[1];
    const float* bias       = (const float*)d_in[2];
    const float* fc1_w      = (const float*)d_in[3];
    const float* fc1_b      = (const float*)d_in[4];
    const float* fc2_w      = (const float*)d_in[5];
    const float* fc2_b      = (const float*)d_in[6];
    const float* kan_base_w = (const float*)d_in[7];
    const float* kan_spline = (const float*)d_in[8];
    const float* kan_scaler = (const float*)d_in[9];
    float* out = (float*)d_out;

    // ws: W3 (72*8192 halves) | Wk3 (72*2048) | Wf3 (8*2048)
    _Float16* W3  = (_Float16*)d_ws;
    _Float16* Wk3 = W3 + (size_t)72 * 8192;
    _Float16* Wf3 = Wk3 + (size_t)72 * 2048;

    w3_transform<<<256, 256, 0, stream>>>(weight, W3);
    wk3_transform<<<80, 256, 0, stream>>>(kan_base_w, kan_spline, kan_scaler,
                                          fc1_w, Wk3, Wf3);
    fused_kernel<<<BT / MS, 256, 0, stream>>>(x, W3, Wk3, Wf3, bias, fc1_b,
                                              fc2_w, fc2_b, out);
}

// Round 7
// 250.523 us; speedup vs baseline: 1.1325x; 1.1325x over previous
//
#include <hip/hip_runtime.h>

#define BT   8192
#define MS   16               // samples per fused block
#define XBUF (MS * 656)       // halves per Xs buffer

typedef _Float16 half8  __attribute__((ext_vector_type(8)));
typedef _Float16 half4v __attribute__((ext_vector_type(4)));
typedef float    floatx4  __attribute__((ext_vector_type(4)));
typedef float    floatx16 __attribute__((ext_vector_type(16)));

// ---------------- K0a: conv weight pre-transform -> W3[step][256n][32c] ----
__global__ __launch_bounds__(256) void w3_transform(
    const float* __restrict__ weight, _Float16* __restrict__ W3)
{
    const int n = blockIdx.x;      // 0..255  (= kbank*64 + o)
    const int c = threadIdx.x;     // 0..255
    const float* src = weight + ((size_t)n * 256 + c) * 9;
    const int cc = c >> 5, ci = c & 31;
    #pragma unroll
    for (int ij = 0; ij < 9; ++ij) {
        W3[((size_t)(cc * 9 + ij) * 256 + n) * 32 + ci] = (_Float16)src[ij];
    }
}

// ---------------- K0b: KAN + fc1 weight pre-transform ---------------------
__global__ __launch_bounds__(256) void wk3_transform(
    const float* __restrict__ base_w, const float* __restrict__ spline_w,
    const float* __restrict__ scaler, const float* __restrict__ fc1_w,
    _Float16* __restrict__ Wk3, _Float16* __restrict__ Wf3)
{
    const int st = blockIdx.x;
    const int tid = threadIdx.x;
    if (st < 72) {
        #pragma unroll
        for (int u = 0; u < 8; ++u) {
            const int idx = u * 256 + tid;       // n*32 + kk
            const int n = idx >> 5, kk = idx & 31;
            const int k = st * 32 + kk;
            float v;
            if (k < 256) {
                v = base_w[n * 256 + k];
            } else {
                const int r = k - 256;
                const int i = r >> 3, g = r & 7;
                v = spline_w[((size_t)n * 256 + i) * 8 + g] * scaler[n * 256 + i];
            }
            Wk3[(size_t)st * 2048 + idx] = (_Float16)v;
        }
    } else {
        const int st2 = st - 72;                 // 0..7
        #pragma unroll
        for (int u = 0; u < 8; ++u) {
            const int idx = u * 256 + tid;
            const int n = idx >> 5, kk = idx & 31;
            Wf3[(size_t)st2 * 2048 + idx] = (_Float16)fc1_w[n * 256 + st2 * 32 + kk];
        }
    }
}

// Uniform cubic B-spline, closed form: only 4 of 8 bases nonzero.
// grid g[t] = (t-3)*0.4 - 1  ->  interval idx = floor((x+2.2)/0.4)
__device__ __forceinline__ void bases8c(float xv, _Float16* dst) {
    const float t = (xv + 2.2f) * 2.5f;
    const float ft = floorf(t);
    const int idx = (int)ft;
    const float u = t - ft, v = 1.f - u;
    const float u2 = u * u, v2 = v * v;
    const float c3 = u2 * u * (1.f / 6.f);                    // B_idx
    const float c2 = (1.f / 6.f) + 0.5f * (u + u2 - u2 * u);  // B_{idx-1}
    const float c1 = (1.f / 6.f) + 0.5f * (v + v2 - v2 * v);  // B_{idx-2}
    const float c0 = v2 * v * (1.f / 6.f);                    // B_{idx-3}
    half8 hb;
    #pragma unroll
    for (int tt = 0; tt < 8; ++tt) {
        const int d = idx - tt;
        float b = 0.f;
        b = (d == 0) ? c3 : b;
        b = (d == 1) ? c2 : b;
        b = (d == 2) ? c1 : b;
        b = (d == 3) ? c0 : b;
        hb[tt] = (_Float16)b;
    }
    *(half8*)dst = hb;
}

// ---------------- Fused: attn + dyn-conv (MFMA) + KAN (MFMA) -> out -------
// 512 threads = 8 waves: wave = (cg = wv&3) x (rh = wv>>2).
// Conv: wave owns o-tile cg for kbanks {2rh, 2rh+1}, all 4 row-tiles.
__global__ __launch_bounds__(512, 4) void fused_kernel(
    const float* __restrict__ x, const _Float16* __restrict__ W3,
    const _Float16* __restrict__ Wk3, const _Float16* __restrict__ Wf3,
    const float* __restrict__ bias, const float* __restrict__ fc1_b,
    const float* __restrict__ fc2_w, const float* __restrict__ fc2_b,
    float* __restrict__ out)
{
    // Overlay: phase A = Xs dbuf [0,41984) + Pl [41984,50432)
    //          phase B = Act (16*2312 fp16 = 73984 B), fpart stored in-place
    __shared__ __align__(16) char smem[MS * 2312 * 2];
    __shared__ float hid_lds[MS * 68];
    __shared__ float attn_s[MS][4];

    _Float16* Xs  = (_Float16*)smem;
    _Float16* Pl  = (_Float16*)(smem + 2 * XBUF * 2);
    _Float16* Act = (_Float16*)smem;

    const int tid = threadIdx.x;
    const int wv = tid >> 6, lane = tid & 63;
    const int nl = lane & 15, q = lane >> 4;
    const int cg = wv & 3, rh = wv >> 2;
    const int b0 = blockIdx.x * MS;

    // conv A-fragment base (halves): sample + pixel + k
    const int posr = nl & 3;
    const int aLane = (nl >> 2) * 656 + ((posr >> 1) * 4 + (posr & 1)) * 40 + q * 8;
    // B-fragment lane offsets for this wave's two kbanks (2rh, 2rh+1)
    const int lbW0 = (((rh * 2 + 0) * 4 + cg) * 16 + nl) * 32 + q * 8;
    const int lbW1 = (((rh * 2 + 1) * 4 + cg) * 16 + nl) * 32 + q * 8;

    // x staging: thread -> (sample s_, channel cch)
    const int s_ = tid >> 5, cch = tid & 31;
    const float* xg = x + ((size_t)(b0 + s_) * 256 + cch) * 16;

    floatx4 acc[4][2];
    #pragma unroll
    for (int rt = 0; rt < 4; ++rt) {
        acc[rt][0] = floatx4{0.f, 0.f, 0.f, 0.f};
        acc[rt][1] = floatx4{0.f, 0.f, 0.f, 0.f};
    }

    // prologue: stage chunk 0 into buf 0, prefetch chunk 1
    floatx16 r = *(const floatx16*)xg;
    {
        _Float16* xd = &Xs[s_ * 656 + cch];
        #pragma unroll
        for (int p = 0; p < 16; ++p) xd[p * 40] = (_Float16)r[p];
        float sm = 0.f;
        #pragma unroll
        for (int p = 0; p < 16; ++p) sm += r[p];
        Pl[s_ * 264 + cch] = (_Float16)(sm * (1.0f / 16.0f));
    }
    r = *(const floatx16*)(xg + 512);
    __syncthreads();

    #pragma unroll 1
    for (int cc = 0; cc < 8; ++cc) {
        const int cur = cc & 1;
        if (cc < 7) {      // stage chunk cc+1 into other buffer
            _Float16* xd = &Xs[(cur ^ 1) * XBUF + s_ * 656 + cch];
            #pragma unroll
            for (int p = 0; p < 16; ++p) xd[p * 40] = (_Float16)r[p];
            float sm = 0.f;
            #pragma unroll
            for (int p = 0; p < 16; ++p) sm += r[p];
            Pl[s_ * 264 + (cc + 1) * 32 + cch] = (_Float16)(sm * (1.0f / 16.0f));
        }
        if (cc < 6) r = *(const floatx16*)(xg + (cc + 2) * 512);

        const _Float16* wst = W3 + (size_t)cc * 9 * 8192;
        const _Float16* xb = &Xs[cur * XBUF + aLane];
        // 2-deep named B prefetch
        half8 bA0 = *(const half8*)(wst + lbW0);
        half8 bB0 = *(const half8*)(wst + lbW1);
        half8 bA1 = *(const half8*)(wst + 8192 + lbW0);
        half8 bB1 = *(const half8*)(wst + 8192 + lbW1);
        #pragma unroll
        for (int ij = 0; ij < 9; ++ij) {
            half8 bA2, bB2;
            if (ij < 7) {
                bA2 = *(const half8*)(wst + (ij + 2) * 8192 + lbW0);
                bB2 = *(const half8*)(wst + (ij + 2) * 8192 + lbW1);
            }
            const int p0 = (ij / 3) * 4 + (ij % 3);
            half8 aF[4];
            #pragma unroll
            for (int rt = 0; rt < 4; ++rt)
                aF[rt] = *(const half8*)&xb[rt * 2624 + p0 * 40];
            #pragma unroll
            for (int rt = 0; rt < 4; ++rt) {
                acc[rt][0] = __builtin_amdgcn_mfma_f32_16x16x32_f16(aF[rt], bA0, acc[rt][0], 0, 0, 0);
                acc[rt][1] = __builtin_amdgcn_mfma_f32_16x16x32_f16(aF[rt], bB0, acc[rt][1], 0, 0, 0);
            }
            bA0 = bA1; bB0 = bB1; bA1 = bA2; bB1 = bB2;
        }
        __syncthreads();
    }

    // ---- fc1 via MFMA (rh==0 waves, h-tile cg); 16 sample-rows valid ----
    if (rh == 0) {
        floatx4 a1 = floatx4{0.f, 0.f, 0.f, 0.f};
        const _Float16* wfb = Wf3 + ((cg * 16 + nl) * 32 + q * 8);
        const _Float16* pb = &Pl[nl * 264 + q * 8];
        #pragma unroll
        for (int st = 0; st < 8; ++st) {
            const half8 aF = *(const half8*)(pb + st * 32);
            const half8 bF = *(const half8*)(wfb + st * 2048);
            a1 = __builtin_amdgcn_mfma_f32_16x16x32_f16(aF, bF, a1, 0, 0, 0);
        }
        const int h = cg * 16 + nl;
        const float fb = fc1_b[h];
        #pragma unroll
        for (int reg = 0; reg < 4; ++reg)
            hid_lds[(q * 4 + reg) * 68 + h] = fmaxf(a1[reg] + fb, 0.f);
    }
    __syncthreads();

    // ---- fc2 + softmax (wave 0: 16 s x 4 kb = 64 lanes) ----
    if (wv == 0) {
        const int s = lane >> 2, kb = lane & 3;
        float l = fc2_b[kb];
        #pragma unroll 8
        for (int h = 0; h < 64; ++h) l += hid_lds[s * 68 + h] * fc2_w[kb * 64 + h];
        float m = fmaxf(l, __shfl_xor(l, 1));
        m = fmaxf(m, __shfl_xor(m, 2));
        const float e = __expf((l - m) * (1.0f / 34.0f));
        float sm = e + __shfl_xor(e, 1);
        sm += __shfl_xor(sm, 2);
        attn_s[s][kb] = e / sm;
    }
    __syncthreads();   // attn ready; Xs/Pl dead -> Act region free

    // ---- epilogue step 1: rh==1 writes attn-weighted partial (f32) into
    //      the Act slot its bases will later occupy ----
    const int o = cg * 16 + nl;
    if (rh == 1) {
        #pragma unroll
        for (int rt = 0; rt < 4; ++rt) {
            const int s = rt * 4 + q;
            const float a2w = attn_s[s][2], a3w = attn_s[s][3];
            #pragma unroll
            for (int e = 0; e < 4; ++e) {
                float* slot = (float*)&Act[s * 2312 + 256 + (o * 4 + e) * 8];
                slot[0] = a2w * acc[rt][0][e] + a3w * acc[rt][1][e];
            }
        }
    }
    __syncthreads();

    // ---- epilogue step 2: rh==0 completes f, silu + bases -> Act ----
    if (rh == 0) {
        const float bb0 = bias[o], bb1 = bias[64 + o], bb2 = bias[128 + o], bb3 = bias[192 + o];
        #pragma unroll
        for (int rt = 0; rt < 4; ++rt) {
            const int s = rt * 4 + q;
            const float a0 = attn_s[s][0], a1 = attn_s[s][1],
                        a2 = attn_s[s][2], a3 = attn_s[s][3];
            const float badd = a0 * bb0 + a1 * bb1 + a2 * bb2 + a3 * bb3;
            float f[4];
            #pragma unroll
            for (int e = 0; e < 4; ++e) {
                const float part = ((float*)&Act[s * 2312 + 256 + (o * 4 + e) * 8])[0];
                f[e] = a0 * acc[rt][0][e] + a1 * acc[rt][1][e] + part + badd;
            }
            half4v sv;
            #pragma unroll
            for (int e = 0; e < 4; ++e) {
                const float ex = __expf(-f[e]);
                sv[e] = (_Float16)(f[e] * __builtin_amdgcn_rcpf(1.f + ex));
            }
            *(half4v*)&Act[s * 2312 + o * 4] = sv;
            #pragma unroll
            for (int e = 0; e < 4; ++e)
                bases8c(f[e], &Act[s * 2312 + 256 + (o * 4 + e) * 8]);
        }
    }
    __syncthreads();

    // ---- KAN GEMM: split-K by rh, o-tile cg, 16 sample-rows ----
    {
        floatx4 a2 = floatx4{0.f, 0.f, 0.f, 0.f};
        const _Float16* wkb = Wk3 + ((size_t)(cg * 16 + nl) * 32 + q * 8);
        const _Float16* ab = &Act[nl * 2312 + q * 8];
        const int st0 = rh * 36;
        half8 kb0 = *(const half8*)(wkb + (size_t)st0 * 2048);
        half8 kb1 = *(const half8*)(wkb + (size_t)(st0 + 1) * 2048);
        #pragma unroll 4
        for (int i = 0; i < 36; ++i) {
            half8 kb2;
            if (i < 34) kb2 = *(const half8*)(wkb + (size_t)(st0 + i + 2) * 2048);
            const half8 aF = *(const half8*)(ab + (st0 + i) * 32);
            a2 = __builtin_amdgcn_mfma_f32_16x16x32_f16(aF, kb0, a2, 0, 0, 0);
            kb0 = kb1; kb1 = kb2;
        }
        if (rh == 1) *(floatx4*)&hid_lds[cg * 256 + lane * 4] = a2;
        __syncthreads();
        if (rh == 0) {
            const floatx4 p = *(const floatx4*)&hid_lds[cg * 256 + lane * 4];
            a2 = a2 + p;
            #pragma unroll
            for (int reg = 0; reg < 4; ++reg)
                out[(size_t)(b0 + q * 4 + reg) * 64 + cg * 16 + nl] = a2[reg];
        }
    }
}

extern "C" void kernel_launch(void* const* d_in, const int* in_sizes, int n_in,
                              void* d_out, int out_size, void* d_ws, size_t ws_size,
                              hipStream_t stream) {
    const float* x          = (const float*)d_in[0];
    const float* weight     = (const float*)d_in[1];
    const float* bias       = (const float*)d_in[2];
    const float* fc1_w      = (const float*)d_in[3];
    const float* fc1_b      = (const float*)d_in[4];
    const float* fc2_w      = (const float*)d_in[5];
    const float* fc2_b      = (const float*)d_in[6];
    const float* kan_base_w = (const float*)d_in[7];
    const float* kan_spline = (const float*)d_in[8];
    const float* kan_scaler = (const float*)d_in[9];
    float* out = (float*)d_out;

    // ws: W3 (72*8192 halves) | Wk3 (72*2048) | Wf3 (8*2048)
    _Float16* W3  = (_Float16*)d_ws;
    _Float16* Wk3 = W3 + (size_t)72 * 8192;
    _Float16* Wf3 = Wk3 + (size_t)72 * 2048;

    w3_transform<<<256, 256, 0, stream>>>(weight, W3);
    wk3_transform<<<80, 256, 0, stream>>>(kan_base_w, kan_spline, kan_scaler,
                                          fc1_w, Wk3, Wf3);
    fused_kernel<<<BT / MS, 512, 0, stream>>>(x, W3, Wk3, Wf3, bias, fc1_b,
                                              fc2_w, fc2_b, out);
}